// Round 15
// baseline (9126.249 us; speedup 1.0000x reference)
//
#include <hip/hip_runtime.h>
#include <cstddef>

using bf16x8 = __attribute__((ext_vector_type(8))) short;
using f32x4  = __attribute__((ext_vector_type(4))) float;

constexpr int Bb = 128;
constexpr int Tt = 256;
constexpr int Hh = 1024;
constexpr int Oo = 64;
constexpr int NBLK = 200;         // 64 h1 + 64 acc2 + 64 u + 8 out
constexpr int FLAG_STRIDE = 32;   // dwords -> 128B between flags
constexpr int RS = 1048;          // LDS row stride (shorts); b128 reads at 8cy floor

__device__ __forceinline__ float bf2f(short s) {
  unsigned int u = ((unsigned int)(unsigned short)s) << 16;
  float f;
  __builtin_memcpy(&f, &u, 4);
  return f;
}
__device__ __forceinline__ short f2bf(float f) {
  unsigned int u;
  __builtin_memcpy(&u, &f, 4);
  u += 0x7fffu + ((u >> 16) & 1u);  // round-to-nearest-even
  return (short)(u >> 16);
}
__device__ __forceinline__ bf16x8 as_bf(int4 v) {
  union { int4 i; bf16x8 b; } u; u.i = v; return u.b;
}
__device__ __forceinline__ float ldf(const float* p) {
  return __hip_atomic_load((float*)p, __ATOMIC_RELAXED, __HIP_MEMORY_SCOPE_AGENT);
}
__device__ __forceinline__ void stf(float* p, float v) {
  __hip_atomic_store(p, v, __ATOMIC_RELAXED, __HIP_MEMORY_SCOPE_AGENT);
}
__device__ __forceinline__ unsigned ldu(const unsigned* p) {
  return __hip_atomic_load((unsigned*)p, __ATOMIC_RELAXED, __HIP_MEMORY_SCOPE_AGENT);
}

// Agent-scope (sc1) coherent 16B load — bypasses per-XCD L2, LLC-coherent.
#define LD16A(d, p) asm volatile("global_load_dwordx4 %0, %1, off sc1" \
                                 : "=v"(d) : "v"((const void*)(p)))

// Stage one 16-row x 1024-col bf16 state slab into LDS (flat sc1 loads, one
// exposed LLC latency). 4 waves share the copy (the r14 win).
__device__ __forceinline__ void stage16(short* As, const short* src, int tid) {
  const int row = tid >> 4;          // 0..15
  const int c0  = (tid & 15) * 8;    // shorts
  const short* gp = src + (size_t)row * Hh + c0;
  short* lp = As + row * RS + c0;
  int4 r[8];
#pragma unroll
  for (int j = 0; j < 8; ++j) LD16A(r[j], gp + j * 128);
  asm volatile("s_waitcnt vmcnt(0)" ::: "memory");
#pragma unroll
  for (int j = 0; j < 8; ++j) *(int4*)(lp + j * 128) = r[j];
}

// B preload: first 8 chunks (16 plain cached loads) issued BEFORE stage16 so
// their L2/LLC latency overlaps the A-stage round trip (r14 serialized them
// after __syncthreads — part of the ~9us/phase B-side cost).
__device__ __forceinline__ void preload_B(int4 (&b0v)[8], int4 (&b1v)[8],
    const short* __restrict__ Bw, int bstride, int colw, int lm, int q) {
  const short* bp0 = Bw + (size_t)(colw + lm) * bstride + q * 8;
  const short* bp1 = bp0 + (size_t)16 * bstride;
#pragma unroll
  for (int c = 0; c < 8; ++c) {
    b0v[c] = *(const int4*)(bp0 + c * 32);
    b1v[c] = *(const int4*)(bp1 + c * 32);
  }
}

// Wave pass: 16 rows (LDS) x 32 cols, K=1024, 8-deep rolling B pipeline
// (r9-proven). 16 loads in flight/wave = 16KB; x4 waves = 64KB/CU >> the
// ~17KB BW-delay product -> B goes from latency-starved (r14's 2-chunk
// lookahead vs 200-600cy latency) to stream-bound (~1.9us/CU/phase).
__device__ __forceinline__ void lds_pass2(const short* As, int lm, int q,
    const short* __restrict__ Bw, int bstride, int colw,
    int4 (&b0v)[8], int4 (&b1v)[8], f32x4 (&acc)[2]) {
  const short* ap  = As + lm * RS + q * 8;
  const short* bp0 = Bw + (size_t)(colw + lm) * bstride + q * 8;
  const short* bp1 = bp0 + (size_t)16 * bstride;
#pragma unroll
  for (int c = 0; c < 32; ++c) {
    const int s = c & 7;
    const bf16x8 b0 = as_bf(b0v[s]);
    const bf16x8 b1 = as_bf(b1v[s]);
    if (c + 8 < 32) {
      b0v[s] = *(const int4*)(bp0 + (c + 8) * 32);
      b1v[s] = *(const int4*)(bp1 + (c + 8) * 32);
    }
    const bf16x8 a = as_bf(*(const int4*)(ap + c * 32));
    acc[0] = __builtin_amdgcn_mfma_f32_16x16x32_bf16(a, b0, acc[0], 0, 0, 0);
    acc[1] = __builtin_amdgcn_mfma_f32_16x16x32_bf16(a, b1, acc[1], 0, 0, 0);
  }
}

// Hierarchical RMW-free grid barrier (identical structure to rounds 9-14).
__device__ __forceinline__ void grid_barrier(unsigned* flags, unsigned* go,
                                             unsigned gen, int bid, int tid) {
  __builtin_amdgcn_s_waitcnt(0);
  __syncthreads();
  if (tid == 0)
    __hip_atomic_store(flags + (size_t)bid * FLAG_STRIDE, gen,
                       __ATOMIC_RELAXED, __HIP_MEMORY_SCOPE_AGENT);
  if (bid == 0) {
    if (tid < 64) {
      const unsigned* f = flags + (size_t)tid * FLAG_STRIDE;
      for (;;) {
        const unsigned a = ldu(f);
        const unsigned b = ldu(f +  64 * FLAG_STRIDE);
        const unsigned c = ldu(f + 128 * FLAG_STRIDE);
        const unsigned d = ldu(f + 192 * FLAG_STRIDE);
        if (__all((a >= gen) && (b >= gen) && (c >= gen) && (d >= gen))) break;
        __builtin_amdgcn_s_sleep(2);
      }
      if (tid == 0)
        __hip_atomic_store(go, gen, __ATOMIC_RELAXED, __HIP_MEMORY_SCOPE_AGENT);
    }
  } else if (tid < 64) {
    while (ldu(go) < gen)
      __builtin_amdgcn_s_sleep(2);
  }
  __syncthreads();
  asm volatile("" ::: "memory");
}

// C/D layout (verified m89/m91): col = lane&15, row = (lane>>4)*4 + reg
#define TL(MB, CW, ACC, ...) do {                                          \
    _Pragma("unroll")                                                      \
    for (int n = 0; n < 2; ++n) {                                          \
      _Pragma("unroll")                                                    \
      for (int r = 0; r < 4; ++r) {                                        \
        const int row = (MB) + q * 4 + r;                                  \
        const int col = (CW) + n * 16 + lm;                                \
        const float z = (ACC)[n][r];                                       \
        __VA_ARGS__;                                                       \
      } } } while (0)

#define ST_BF16_PAIR(BASE, ROW, COL, HV) do {                              \
    const int _ov = __shfl_xor((int)(unsigned short)(HV), 1, 64);          \
    if ((lm & 1) == 0) {                                                   \
      const unsigned _pk = (unsigned)(unsigned short)(HV) | ((unsigned)_ov << 16); \
      __hip_atomic_store((unsigned*)((BASE) + (ROW) * Hh + (COL)), _pk,    \
                         __ATOMIC_RELAXED, __HIP_MEMORY_SCOPE_AGENT);      \
    } } while (0)

#define SET_ACC(ACC, V0, V1) do {                                          \
    (ACC)[0] = (f32x4){(V0), (V0), (V0), (V0)};                            \
    (ACC)[1] = (f32x4){(V1), (V1), (V1), (V1)};                            \
  } while (0)

struct RP {
  short* h1a; short* h1b; short* h2bf;
  float* h2f; float* uf; float* ug1f; float* acc2f; float* o1f;
  const short* prex;
  const short* whh1; const short* wih2; const short* whh2;
  const short* wg; const short* wo1; const short* wo2;
  const float* b_ih2; const float* b_hh2;
  const float* bg; const float* bo1; const float* bo2;
  float* out;
  unsigned* flags;
  unsigned* go;
};

// r14 structure: block = 256 thr = 4 waves sharing one staged 16-row A-slab;
// each wave covers 32 cols. colgroup = g&7 == bid%8 -> XCD-aligned weights.
//  Phase A: bid 0-63 h1 | 64-127 acc2 | 128-191 u-gate | 192-199 out(t-1)
//  Phase B: bid 0-63 h2 blend | 64-127 ug1 | 192-199 o1 head | others idle
__global__ void __launch_bounds__(256, 1) rnn_kernel(RP p) {
  __shared__ short As[16 * RS];     // 33536 B
  const int tid = threadIdx.x;
  const int lane = tid & 63;
  const int wv = tid >> 6;
  const int lm = lane & 15;
  const int q = lane >> 4;
  const int bid = blockIdx.x;

  int roleA, roleB, g;
  if      (bid < 64)  { roleA = 0; roleB = 4; g = bid; }
  else if (bid < 128) { roleA = 1; roleB = 5; g = bid - 64; }
  else if (bid < 192) { roleA = 2; roleB = 7; g = bid - 128; }
  else                { roleA = 3; roleB = 6; g = bid - 192; }
  const bool small = (roleA == 3);              // out/o1 blocks: 16r x 64c
  const int mb   = small ? g * 16 : (g >> 3) * 16;
  const int colw = small ? wv * 32 : (g & 7) * 128 + wv * 32;

  float bA0 = 0.f, bA1 = 0.f, bB0 = 0.f, bB1 = 0.f;
  {
    const int c0 = colw + lm, c1 = colw + 16 + lm;
    if (roleA == 1) { bA0 = p.b_ih2[c0] + p.b_hh2[c0]; bA1 = p.b_ih2[c1] + p.b_hh2[c1]; }
    else if (roleA == 2) { bA0 = p.bg[c0]; bA1 = p.bg[c1]; }
    else if (roleA == 3 && wv < 2) { bA0 = p.bo2[c0]; bA1 = p.bo2[c1]; }
    if (roleB == 6 && wv < 2) { bB0 = p.bo1[c0]; bB1 = p.bo1[c1]; }
  }
  const size_t HS = (size_t)Bb * Hh;

  f32x4 acc[2];
  int4 b0v[8], b1v[8];
  unsigned gen = 0;
  for (int t = 0; t < Tt; ++t) {
    const short* h1in  = (t & 1) ? p.h1b : p.h1a;
    short*       h1out = (t & 1) ? p.h1a : p.h1b;
    // ---------------- Phase A ----------------
    if (roleA == 0) {
      short prs[2][4];
      const short* pr = p.prex + (size_t)t * HS;
#pragma unroll
      for (int n = 0; n < 2; ++n)
#pragma unroll
        for (int r = 0; r < 4; ++r)
          prs[n][r] = pr[(size_t)(mb + q * 4 + r) * Hh + colw + n * 16 + lm];
      preload_B(b0v, b1v, p.whh1, Hh, colw, lm, q);
      stage16(As, h1in + (size_t)mb * Hh, tid);
      __syncthreads();
      SET_ACC(acc, 0.f, 0.f);
      lds_pass2(As, lm, q, p.whh1, Hh, colw, b0v, b1v, acc);
      TL(mb, colw, acc, {
        const short hv = f2bf(tanhf(z + bf2f(prs[n][r])));
        ST_BF16_PAIR(h1out, row, col, hv);
      });
    } else if (roleA == 1) {
      preload_B(b0v, b1v, p.whh2, Hh, colw, lm, q);
      stage16(As, p.h2bf + (size_t)mb * Hh, tid);
      __syncthreads();
      SET_ACC(acc, bA0, bA1);
      lds_pass2(As, lm, q, p.whh2, Hh, colw, b0v, b1v, acc);
      TL(mb, colw, acc, { stf(p.acc2f + row * Hh + col, z); });
    } else if (roleA == 2) {
      if (t > 0) {
        float ex[2][4];
#pragma unroll
        for (int n = 0; n < 2; ++n)
#pragma unroll
          for (int r = 0; r < 4; ++r)
            ex[n][r] = ldf(p.ug1f + (mb + q * 4 + r) * Hh + colw + n * 16 + lm);
        preload_B(b0v, b1v, p.wg + Hh, 2 * Hh, colw, lm, q);
        stage16(As, p.h2bf + (size_t)mb * Hh, tid);
        __syncthreads();
        SET_ACC(acc, bA0, bA1);
        lds_pass2(As, lm, q, p.wg + Hh, 2 * Hh, colw, b0v, b1v, acc);
        TL(mb, colw, acc, {
          const float s = z + ex[n][r];
          stf(p.uf + row * Hh + col, 1.0f / (1.0f + expf(-s)));
        });
      }
    } else {
      if (t > 0) {
        float ex[2][4];
        if (wv < 2) {
#pragma unroll
          for (int n = 0; n < 2; ++n)
#pragma unroll
            for (int r = 0; r < 4; ++r)
              ex[n][r] = ldf(p.o1f + (mb + q * 4 + r) * Oo + colw + n * 16 + lm);
          preload_B(b0v, b1v, p.wo2, Hh, colw, lm, q);
        }
        stage16(As, p.h2bf + (size_t)mb * Hh, tid);
        __syncthreads();
        if (wv < 2) {
          SET_ACC(acc, bA0, bA1);
          lds_pass2(As, lm, q, p.wo2, Hh, colw, b0v, b1v, acc);
          TL(mb, colw, acc, {
            p.out[(size_t)row * (Tt * Oo) + (size_t)(t - 1) * Oo + col] =
                ex[n][r] + tanhf(z);
          });
        }
      }
    }
    ++gen;
    grid_barrier(p.flags, p.go, gen, bid, tid);
    // ---------------- Phase B ----------------
    if (roleB == 4) {
      float a2[2][4], uu[2][4], h2o[2][4];
#pragma unroll
      for (int n = 0; n < 2; ++n)
#pragma unroll
        for (int r = 0; r < 4; ++r) {
          const int idx = (mb + q * 4 + r) * Hh + colw + n * 16 + lm;
          a2[n][r]  = ldf(p.acc2f + idx);
          uu[n][r]  = ldf(p.uf + idx);
          h2o[n][r] = p.h2f[idx];        // block-local plain RW
        }
      preload_B(b0v, b1v, p.wih2, Hh, colw, lm, q);
      stage16(As, h1out + (size_t)mb * Hh, tid);
      __syncthreads();
      SET_ACC(acc, 0.f, 0.f);
      lds_pass2(As, lm, q, p.wih2, Hh, colw, b0v, b1v, acc);
      TL(mb, colw, acc, {
        const int idx = row * Hh + col;
        const float hn = tanhf(z + a2[n][r]);
        const float nv = fmaf(uu[n][r], hn - h2o[n][r], h2o[n][r]);
        p.h2f[idx] = nv;
        const short hv = f2bf(nv);
        ST_BF16_PAIR(p.h2bf, row, col, hv);
      });
    } else if (roleB == 5) {
      preload_B(b0v, b1v, p.wg, 2 * Hh, colw, lm, q);
      stage16(As, h1out + (size_t)mb * Hh, tid);
      __syncthreads();
      SET_ACC(acc, 0.f, 0.f);
      lds_pass2(As, lm, q, p.wg, 2 * Hh, colw, b0v, b1v, acc);
      TL(mb, colw, acc, { stf(p.ug1f + row * Hh + col, z); });
    } else if (roleB == 6) {
      if (wv < 2) preload_B(b0v, b1v, p.wo1, Hh, colw, lm, q);
      stage16(As, h1out + (size_t)mb * Hh, tid);
      __syncthreads();
      if (wv < 2) {
        SET_ACC(acc, bB0, bB1);
        lds_pass2(As, lm, q, p.wo1, Hh, colw, b0v, b1v, acc);
        TL(mb, colw, acc, { stf(p.o1f + row * Oo + col, tanhf(z)); });
      }
    }
    ++gen;
    grid_barrier(p.flags, p.go, gen, bid, tid);
  }
  // tail: out rows for t = Tt-1
  if (roleA == 3) {
    float ex[2][4];
    if (wv < 2) {
#pragma unroll
      for (int n = 0; n < 2; ++n)
#pragma unroll
        for (int r = 0; r < 4; ++r)
          ex[n][r] = ldf(p.o1f + (mb + q * 4 + r) * Oo + colw + n * 16 + lm);
      preload_B(b0v, b1v, p.wo2, Hh, colw, lm, q);
    }
    stage16(As, p.h2bf + (size_t)mb * Hh, tid);
    __syncthreads();
    if (wv < 2) {
      SET_ACC(acc, bA0, bA1);
      lds_pass2(As, lm, q, p.wo2, Hh, colw, b0v, b1v, acc);
      TL(mb, colw, acc, {
        p.out[(size_t)row * (Tt * Oo) + (size_t)(Tt - 1) * Oo + col] =
            ex[n][r] + tanhf(z);
      });
    }
  }
}

// pre_x[t][b][j] = x[b,t,:] @ W_ih1[j,:] + b_ih1[j] + b_hh1[j]  (stored bf16)
__global__ void __launch_bounds__(256) prex_kernel(
    const float* __restrict__ x, const float* __restrict__ wih1,
    const float* __restrict__ b_ih1, const float* __restrict__ b_hh1,
    short* __restrict__ prex) {
  const int tid = threadIdx.x;
  const int lane = tid & 63;
  const int wv = tid >> 6;
  const int lm = lane & 15;
  const int q = lane >> 4;
  const int bm = blockIdx.x >> 4;
  const int bn = blockIdx.x & 15;
  const int rowbase = bm * 64;
  const int col = bn * 64 + wv * 16 + lm;

  const f32x4 z4 = {0.f, 0.f, 0.f, 0.f};
  f32x4 acc[4];
#pragma unroll
  for (int mt = 0; mt < 4; ++mt) acc[mt] = z4;

#pragma unroll
  for (int kc = 0; kc < 2; ++kc) {
    const float* bp = wih1 + col * 64 + kc * 32 + q * 8;
    bf16x8 bf;
#pragma unroll
    for (int j = 0; j < 8; ++j) bf[j] = f2bf(bp[j]);
#pragma unroll
    for (int mt = 0; mt < 4; ++mt) {
      const float* ap = x + (size_t)(rowbase + mt * 16 + lm) * 64 + kc * 32 + q * 8;
      bf16x8 af;
#pragma unroll
      for (int j = 0; j < 8; ++j) af[j] = f2bf(ap[j]);
      acc[mt] = __builtin_amdgcn_mfma_f32_16x16x32_bf16(af, bf, acc[mt], 0, 0, 0);
    }
  }
  const float bia = b_ih1[col] + b_hh1[col];
#pragma unroll
  for (int mt = 0; mt < 4; ++mt) {
#pragma unroll
    for (int r = 0; r < 4; ++r) {
      const int row = rowbase + mt * 16 + q * 4 + r;  // row = b*256 + t
      const int b  = row >> 8;
      const int tt = row & 255;
      prex[((size_t)tt * Bb + b) * Hh + col] = f2bf(acc[mt][r] + bia);
    }
  }
}

__global__ void conv_kernel(const float* __restrict__ s, short* __restrict__ d, int n) {
  int i = blockIdx.x * blockDim.x + threadIdx.x;
  const int stride = gridDim.x * blockDim.x;
  for (; i < n; i += stride) d[i] = f2bf(s[i]);
}

__global__ void init_kernel(short* h1a, short* h1b, short* h2bf, float* h2f,
                            float* uf, unsigned* flags, unsigned* go) {
  const int i = blockIdx.x * blockDim.x + threadIdx.x;  // exactly 128*1024
  h1a[i] = 0; h1b[i] = 0; h2bf[i] = 0; h2f[i] = 0.f; uf[i] = 1.0f;
  if (i < 256) flags[i * FLAG_STRIDE] = (i < NBLK) ? 0u : 0xFFFFFFFFu;
  if (i == 0) *go = 0u;
}

extern "C" void kernel_launch(void* const* d_in, const int* in_sizes, int n_in,
                              void* d_out, int out_size, void* d_ws, size_t ws_size,
                              hipStream_t stream) {
  (void)in_sizes; (void)n_in; (void)out_size; (void)ws_size;
  const float* x      = (const float*)d_in[0];
  const float* W_ih1  = (const float*)d_in[1];
  const float* b_ih1  = (const float*)d_in[2];
  const float* W_hh1  = (const float*)d_in[3];
  const float* b_hh1  = (const float*)d_in[4];
  const float* W_ih2  = (const float*)d_in[5];
  const float* b_ih2  = (const float*)d_in[6];
  const float* W_hh2  = (const float*)d_in[7];
  const float* b_hh2  = (const float*)d_in[8];
  const float* Wg     = (const float*)d_in[9];
  const float* bg     = (const float*)d_in[10];
  const float* Wo1    = (const float*)d_in[11];
  const float* bo1    = (const float*)d_in[12];
  const float* Wo2    = (const float*)d_in[13];
  const float* bo2    = (const float*)d_in[14];

  char* ws = (char*)d_ws;
  size_t off = 0;
  auto alloc = [&](size_t bytes) -> void* {
    void* ptr = ws + off;
    off += (bytes + 255) & ~(size_t)255;
    return ptr;
  };
  short* whh1 = (short*)alloc((size_t)Hh * Hh * 2);
  short* wih2 = (short*)alloc((size_t)Hh * Hh * 2);
  short* whh2 = (short*)alloc((size_t)Hh * Hh * 2);
  short* wg   = (short*)alloc((size_t)Hh * 2 * Hh * 2);
  short* wo1  = (short*)alloc((size_t)Oo * Hh * 2);
  short* wo2  = (short*)alloc((size_t)Oo * Hh * 2);
  short* prex = (short*)alloc((size_t)Bb * Tt * Hh * 2);
  short* h1a  = (short*)alloc((size_t)Bb * Hh * 2);
  short* h1b  = (short*)alloc((size_t)Bb * Hh * 2);
  short* h2bf = (short*)alloc((size_t)Bb * Hh * 2);
  float* h2f  = (float*)alloc((size_t)Bb * Hh * 4);
  float* uf   = (float*)alloc((size_t)Bb * Hh * 4);
  float* ug1f = (float*)alloc((size_t)Bb * Hh * 4);
  float* acc2f= (float*)alloc((size_t)Bb * Hh * 4);
  float* o1f  = (float*)alloc((size_t)Bb * Oo * 4);
  unsigned* flags = (unsigned*)alloc(256 * FLAG_STRIDE * 4);   // 32 KB
  unsigned* go    = (unsigned*)alloc(256);

  conv_kernel<<<1024, 256, 0, stream>>>(W_hh1, whh1, Hh * Hh);
  conv_kernel<<<1024, 256, 0, stream>>>(W_ih2, wih2, Hh * Hh);
  conv_kernel<<<1024, 256, 0, stream>>>(W_hh2, whh2, Hh * Hh);
  conv_kernel<<<2048, 256, 0, stream>>>(Wg,    wg,   Hh * 2 * Hh);
  conv_kernel<<<256,  256, 0, stream>>>(Wo1,   wo1,  Oo * Hh);
  conv_kernel<<<256,  256, 0, stream>>>(Wo2,   wo2,  Oo * Hh);
  init_kernel<<<512, 256, 0, stream>>>(h1a, h1b, h2bf, h2f, uf, flags, go);
  prex_kernel<<<8192, 256, 0, stream>>>(x, W_ih1, b_ih1, b_hh1, prex);

  RP p;
  p.h1a = h1a; p.h1b = h1b; p.h2bf = h2bf;
  p.h2f = h2f; p.uf = uf; p.ug1f = ug1f; p.acc2f = acc2f; p.o1f = o1f;
  p.prex = prex;
  p.whh1 = whh1; p.wih2 = wih2; p.whh2 = whh2;
  p.wg = wg; p.wo1 = wo1; p.wo2 = wo2;
  p.b_ih2 = b_ih2; p.b_hh2 = b_hh2;
  p.bg = bg; p.bo1 = bo1; p.bo2 = bo2;
  p.out = (float*)d_out;
  p.flags = flags;
  p.go = go;

  rnn_kernel<<<NBLK, 256, 0, stream>>>(p);
}

// Round 16
// 7955.904 us; speedup vs baseline: 1.1471x; 1.1471x over previous
//
#include <hip/hip_runtime.h>
#include <cstddef>

using bf16x8 = __attribute__((ext_vector_type(8))) short;
using f32x4  = __attribute__((ext_vector_type(4))) float;

constexpr int Bb = 128;
constexpr int Tt = 256;
constexpr int Hh = 1024;
constexpr int Oo = 64;
constexpr int NBLK = 200;         // 64 h1 + 64 acc2 + 64 u + 8 out
constexpr int RS = 1048;          // LDS row stride (shorts); b128 reads at 8cy floor

__device__ __forceinline__ float bf2f(short s) {
  unsigned int u = ((unsigned int)(unsigned short)s) << 16;
  float f;
  __builtin_memcpy(&f, &u, 4);
  return f;
}
__device__ __forceinline__ short f2bf(float f) {
  unsigned int u;
  __builtin_memcpy(&u, &f, 4);
  u += 0x7fffu + ((u >> 16) & 1u);  // round-to-nearest-even
  return (short)(u >> 16);
}
__device__ __forceinline__ bf16x8 as_bf(int4 v) {
  union { int4 i; bf16x8 b; } u; u.i = v; return u.b;
}
__device__ __forceinline__ float ldf(const float* p) {
  return __hip_atomic_load((float*)p, __ATOMIC_RELAXED, __HIP_MEMORY_SCOPE_AGENT);
}
__device__ __forceinline__ void stf(float* p, float v) {
  __hip_atomic_store(p, v, __ATOMIC_RELAXED, __HIP_MEMORY_SCOPE_AGENT);
}
__device__ __forceinline__ unsigned ldu(const unsigned* p) {
  return __hip_atomic_load((unsigned*)p, __ATOMIC_RELAXED, __HIP_MEMORY_SCOPE_AGENT);
}

// Agent-scope (sc1) coherent 16B load — bypasses per-XCD L2, LLC-coherent.
#define LD16A(d, p) asm volatile("global_load_dwordx4 %0, %1, off sc1" \
                                 : "=v"(d) : "v"((const void*)(p)))

// Stage one 16-row x 1024-col bf16 state slab into LDS (flat sc1 loads, one
// exposed LLC latency). 4 waves share the copy (the r14 win).
__device__ __forceinline__ void stage16(short* As, const short* src, int tid) {
  const int row = tid >> 4;          // 0..15
  const int c0  = (tid & 15) * 8;    // shorts
  const short* gp = src + (size_t)row * Hh + c0;
  short* lp = As + row * RS + c0;
  int4 r[8];
#pragma unroll
  for (int j = 0; j < 8; ++j) LD16A(r[j], gp + j * 128);
  asm volatile("s_waitcnt vmcnt(0)" ::: "memory");
#pragma unroll
  for (int j = 0; j < 8; ++j) *(int4*)(lp + j * 128) = r[j];
}

// Wave pass: 16 rows (LDS) x 32 cols, K=1024. B from L2-resident weights,
// 3-deep pipeline — r14-exact. (r15's 8-deep ring regressed: +40 VGPRs at
// the 256-arch cap wrecked B-locality, FETCH 786MB -> 4GB. 3-deep is the knee.)
__device__ __forceinline__ void lds_pass2(const short* As, int lm, int q,
    const short* __restrict__ Bw, int bstride, int colw, f32x4 (&acc)[2]) {
  const short* ap  = As + lm * RS + q * 8;
  const short* bp0 = Bw + (size_t)(colw + lm) * bstride + q * 8;
  const short* bp1 = bp0 + (size_t)16 * bstride;
  int4 b0v[3], b1v[3];
  b0v[0] = *(const int4*)(bp0);      b1v[0] = *(const int4*)(bp1);
  b0v[1] = *(const int4*)(bp0 + 32); b1v[1] = *(const int4*)(bp1 + 32);
#pragma unroll
  for (int c = 0; c < 32; ++c) {
    if (c + 2 < 32) {
      b0v[(c + 2) % 3] = *(const int4*)(bp0 + (c + 2) * 32);
      b1v[(c + 2) % 3] = *(const int4*)(bp1 + (c + 2) * 32);
    }
    const bf16x8 a = as_bf(*(const int4*)(ap + c * 32));
    acc[0] = __builtin_amdgcn_mfma_f32_16x16x32_bf16(a, as_bf(b0v[c % 3]), acc[0], 0, 0, 0);
    acc[1] = __builtin_amdgcn_mfma_f32_16x16x32_bf16(a, as_bf(b1v[c % 3]), acc[1], 0, 0, 0);
  }
}

// Single-hop packed-flag barrier. Arrivals = parallel 4B stores into a
// PACKED flag array (200 flags = 7 cache lines). Every block polls all
// flags directly: 4 coalesced dword loads/wave = 8 line-requests per round
// (r8's storm was 256 DISTINCT lines/wave; packing kills that). This deletes
// the r9-r14 two-hop chain (block0 aggregate -> go publish): exit latency =
// last-arrival + one poll round. s_sleep(8) caps poll traffic ~7.5K lines/us.
__device__ __forceinline__ void grid_barrier(unsigned* flags, unsigned gen,
                                             int bid, int tid) {
  __builtin_amdgcn_s_waitcnt(0);   // drain this wave's sc1 state stores
  __syncthreads();
  if (tid == 0)
    __hip_atomic_store(flags + bid, gen, __ATOMIC_RELAXED, __HIP_MEMORY_SCOPE_AGENT);
  if (tid < 64) {
    for (;;) {
      const unsigned a = ldu(flags + tid);
      const unsigned b = ldu(flags + tid + 64);
      const unsigned c = ldu(flags + tid + 128);
      const unsigned d = ldu(flags + tid + 192);
      if (__all((a >= gen) && (b >= gen) && (c >= gen) && (d >= gen))) break;
      __builtin_amdgcn_s_sleep(8);
    }
  }
  __syncthreads();
  asm volatile("" ::: "memory");
}

// C/D layout (verified m89/m91): col = lane&15, row = (lane>>4)*4 + reg
#define TL(MB, CW, ACC, ...) do {                                          \
    _Pragma("unroll")                                                      \
    for (int n = 0; n < 2; ++n) {                                          \
      _Pragma("unroll")                                                    \
      for (int r = 0; r < 4; ++r) {                                        \
        const int row = (MB) + q * 4 + r;                                  \
        const int col = (CW) + n * 16 + lm;                                \
        const float z = (ACC)[n][r];                                       \
        __VA_ARGS__;                                                       \
      } } } while (0)

#define ST_BF16_PAIR(BASE, ROW, COL, HV) do {                              \
    const int _ov = __shfl_xor((int)(unsigned short)(HV), 1, 64);          \
    if ((lm & 1) == 0) {                                                   \
      const unsigned _pk = (unsigned)(unsigned short)(HV) | ((unsigned)_ov << 16); \
      __hip_atomic_store((unsigned*)((BASE) + (ROW) * Hh + (COL)), _pk,    \
                         __ATOMIC_RELAXED, __HIP_MEMORY_SCOPE_AGENT);      \
    } } while (0)

#define SET_ACC(ACC, V0, V1) do {                                          \
    (ACC)[0] = (f32x4){(V0), (V0), (V0), (V0)};                            \
    (ACC)[1] = (f32x4){(V1), (V1), (V1), (V1)};                            \
  } while (0)

struct RP {
  short* h1a; short* h1b; short* h2bf;
  float* h2f; float* uf; float* ug1f; float* acc2f; float* o1f;
  const short* prex;
  const short* whh1; const short* wih2; const short* whh2;
  const short* wg; const short* wo1; const short* wo2;
  const float* b_ih2; const float* b_hh2;
  const float* bg; const float* bo1; const float* bo2;
  float* out;
  unsigned* flags;
};

// r14 structure: block = 256 thr = 4 waves sharing one staged 16-row A-slab;
// each wave covers 32 cols. colgroup = g&7 == bid%8 -> XCD-aligned weights.
//  Phase A: bid 0-63 h1 | 64-127 acc2 | 128-191 u-gate | 192-199 out(t-1)
//  Phase B: bid 0-63 h2 blend | 64-127 ug1 | 192-199 o1 head | others idle
__global__ void __launch_bounds__(256, 1) rnn_kernel(RP p) {
  __shared__ short As[16 * RS];     // 33536 B
  const int tid = threadIdx.x;
  const int lane = tid & 63;
  const int wv = tid >> 6;
  const int lm = lane & 15;
  const int q = lane >> 4;
  const int bid = blockIdx.x;

  int roleA, roleB, g;
  if      (bid < 64)  { roleA = 0; roleB = 4; g = bid; }
  else if (bid < 128) { roleA = 1; roleB = 5; g = bid - 64; }
  else if (bid < 192) { roleA = 2; roleB = 7; g = bid - 128; }
  else                { roleA = 3; roleB = 6; g = bid - 192; }
  const bool small = (roleA == 3);              // out/o1 blocks: 16r x 64c
  const int mb   = small ? g * 16 : (g >> 3) * 16;
  const int colw = small ? wv * 32 : (g & 7) * 128 + wv * 32;

  float bA0 = 0.f, bA1 = 0.f, bB0 = 0.f, bB1 = 0.f;
  {
    const int c0 = colw + lm, c1 = colw + 16 + lm;
    if (roleA == 1) { bA0 = p.b_ih2[c0] + p.b_hh2[c0]; bA1 = p.b_ih2[c1] + p.b_hh2[c1]; }
    else if (roleA == 2) { bA0 = p.bg[c0]; bA1 = p.bg[c1]; }
    else if (roleA == 3 && wv < 2) { bA0 = p.bo2[c0]; bA1 = p.bo2[c1]; }
    if (roleB == 6 && wv < 2) { bB0 = p.bo1[c0]; bB1 = p.bo1[c1]; }
  }
  const size_t HS = (size_t)Bb * Hh;

  f32x4 acc[2];
  unsigned gen = 0;
  for (int t = 0; t < Tt; ++t) {
    const short* h1in  = (t & 1) ? p.h1b : p.h1a;
    short*       h1out = (t & 1) ? p.h1a : p.h1b;
    // ---------------- Phase A ----------------
    if (roleA == 0) {
      short prs[2][4];
      const short* pr = p.prex + (size_t)t * HS;
#pragma unroll
      for (int n = 0; n < 2; ++n)
#pragma unroll
        for (int r = 0; r < 4; ++r)
          prs[n][r] = pr[(size_t)(mb + q * 4 + r) * Hh + colw + n * 16 + lm];
      stage16(As, h1in + (size_t)mb * Hh, tid);
      __syncthreads();
      SET_ACC(acc, 0.f, 0.f);
      lds_pass2(As, lm, q, p.whh1, Hh, colw, acc);
      TL(mb, colw, acc, {
        const short hv = f2bf(tanhf(z + bf2f(prs[n][r])));
        ST_BF16_PAIR(h1out, row, col, hv);
      });
    } else if (roleA == 1) {
      stage16(As, p.h2bf + (size_t)mb * Hh, tid);
      __syncthreads();
      SET_ACC(acc, bA0, bA1);
      lds_pass2(As, lm, q, p.whh2, Hh, colw, acc);
      TL(mb, colw, acc, { stf(p.acc2f + row * Hh + col, z); });
    } else if (roleA == 2) {
      if (t > 0) {
        float ex[2][4];
#pragma unroll
        for (int n = 0; n < 2; ++n)
#pragma unroll
          for (int r = 0; r < 4; ++r)
            ex[n][r] = ldf(p.ug1f + (mb + q * 4 + r) * Hh + colw + n * 16 + lm);
        stage16(As, p.h2bf + (size_t)mb * Hh, tid);
        __syncthreads();
        SET_ACC(acc, bA0, bA1);
        lds_pass2(As, lm, q, p.wg + Hh, 2 * Hh, colw, acc);
        TL(mb, colw, acc, {
          const float s = z + ex[n][r];
          stf(p.uf + row * Hh + col, 1.0f / (1.0f + expf(-s)));
        });
      }
    } else {
      if (t > 0) {
        float ex[2][4];
        if (wv < 2) {
#pragma unroll
          for (int n = 0; n < 2; ++n)
#pragma unroll
            for (int r = 0; r < 4; ++r)
              ex[n][r] = ldf(p.o1f + (mb + q * 4 + r) * Oo + colw + n * 16 + lm);
        }
        stage16(As, p.h2bf + (size_t)mb * Hh, tid);
        __syncthreads();
        if (wv < 2) {
          SET_ACC(acc, bA0, bA1);
          lds_pass2(As, lm, q, p.wo2, Hh, colw, acc);
          TL(mb, colw, acc, {
            p.out[(size_t)row * (Tt * Oo) + (size_t)(t - 1) * Oo + col] =
                ex[n][r] + tanhf(z);
          });
        }
      }
    }
    ++gen;
    grid_barrier(p.flags, gen, bid, tid);
    // ---------------- Phase B ----------------
    if (roleB == 4) {
      float a2[2][4], uu[2][4], h2o[2][4];
#pragma unroll
      for (int n = 0; n < 2; ++n)
#pragma unroll
        for (int r = 0; r < 4; ++r) {
          const int idx = (mb + q * 4 + r) * Hh + colw + n * 16 + lm;
          a2[n][r]  = ldf(p.acc2f + idx);
          uu[n][r]  = ldf(p.uf + idx);
          h2o[n][r] = p.h2f[idx];        // block-local plain RW
        }
      stage16(As, h1out + (size_t)mb * Hh, tid);
      __syncthreads();
      SET_ACC(acc, 0.f, 0.f);
      lds_pass2(As, lm, q, p.wih2, Hh, colw, acc);
      TL(mb, colw, acc, {
        const int idx = row * Hh + col;
        const float hn = tanhf(z + a2[n][r]);
        const float nv = fmaf(uu[n][r], hn - h2o[n][r], h2o[n][r]);
        p.h2f[idx] = nv;
        const short hv = f2bf(nv);
        ST_BF16_PAIR(p.h2bf, row, col, hv);
      });
    } else if (roleB == 5) {
      stage16(As, h1out + (size_t)mb * Hh, tid);
      __syncthreads();
      SET_ACC(acc, 0.f, 0.f);
      lds_pass2(As, lm, q, p.wg, 2 * Hh, colw, acc);
      TL(mb, colw, acc, { stf(p.ug1f + row * Hh + col, z); });
    } else if (roleB == 6) {
      stage16(As, h1out + (size_t)mb * Hh, tid);
      __syncthreads();
      if (wv < 2) {
        SET_ACC(acc, bB0, bB1);
        lds_pass2(As, lm, q, p.wo1, Hh, colw, acc);
        TL(mb, colw, acc, { stf(p.o1f + row * Oo + col, tanhf(z)); });
      }
    }
    ++gen;
    grid_barrier(p.flags, gen, bid, tid);
  }
  // tail: out rows for t = Tt-1
  if (roleA == 3) {
    float ex[2][4];
    if (wv < 2) {
#pragma unroll
      for (int n = 0; n < 2; ++n)
#pragma unroll
        for (int r = 0; r < 4; ++r)
          ex[n][r] = ldf(p.o1f + (mb + q * 4 + r) * Oo + colw + n * 16 + lm);
    }
    stage16(As, p.h2bf + (size_t)mb * Hh, tid);
    __syncthreads();
    if (wv < 2) {
      SET_ACC(acc, bA0, bA1);
      lds_pass2(As, lm, q, p.wo2, Hh, colw, acc);
      TL(mb, colw, acc, {
        p.out[(size_t)row * (Tt * Oo) + (size_t)(Tt - 1) * Oo + col] =
            ex[n][r] + tanhf(z);
      });
    }
  }
}

// pre_x[t][b][j] = x[b,t,:] @ W_ih1[j,:] + b_ih1[j] + b_hh1[j]  (stored bf16)
__global__ void __launch_bounds__(256) prex_kernel(
    const float* __restrict__ x, const float* __restrict__ wih1,
    const float* __restrict__ b_ih1, const float* __restrict__ b_hh1,
    short* __restrict__ prex) {
  const int tid = threadIdx.x;
  const int lane = tid & 63;
  const int wv = tid >> 6;
  const int lm = lane & 15;
  const int q = lane >> 4;
  const int bm = blockIdx.x >> 4;
  const int bn = blockIdx.x & 15;
  const int rowbase = bm * 64;
  const int col = bn * 64 + wv * 16 + lm;

  const f32x4 z4 = {0.f, 0.f, 0.f, 0.f};
  f32x4 acc[4];
#pragma unroll
  for (int mt = 0; mt < 4; ++mt) acc[mt] = z4;

#pragma unroll
  for (int kc = 0; kc < 2; ++kc) {
    const float* bp = wih1 + col * 64 + kc * 32 + q * 8;
    bf16x8 bf;
#pragma unroll
    for (int j = 0; j < 8; ++j) bf[j] = f2bf(bp[j]);
#pragma unroll
    for (int mt = 0; mt < 4; ++mt) {
      const float* ap = x + (size_t)(rowbase + mt * 16 + lm) * 64 + kc * 32 + q * 8;
      bf16x8 af;
#pragma unroll
      for (int j = 0; j < 8; ++j) af[j] = f2bf(ap[j]);
      acc[mt] = __builtin_amdgcn_mfma_f32_16x16x32_bf16(af, bf, acc[mt], 0, 0, 0);
    }
  }
  const float bia = b_ih1[col] + b_hh1[col];
#pragma unroll
  for (int mt = 0; mt < 4; ++mt) {
#pragma unroll
    for (int r = 0; r < 4; ++r) {
      const int row = rowbase + mt * 16 + q * 4 + r;  // row = b*256 + t
      const int b  = row >> 8;
      const int tt = row & 255;
      prex[((size_t)tt * Bb + b) * Hh + col] = f2bf(acc[mt][r] + bia);
    }
  }
}

__global__ void conv_kernel(const float* __restrict__ s, short* __restrict__ d, int n) {
  int i = blockIdx.x * blockDim.x + threadIdx.x;
  const int stride = gridDim.x * blockDim.x;
  for (; i < n; i += stride) d[i] = f2bf(s[i]);
}

__global__ void init_kernel(short* h1a, short* h1b, short* h2bf, float* h2f,
                            float* uf, unsigned* flags) {
  const int i = blockIdx.x * blockDim.x + threadIdx.x;  // exactly 128*1024
  h1a[i] = 0; h1b[i] = 0; h2bf[i] = 0; h2f[i] = 0.f; uf[i] = 1.0f;
  if (i < 256) flags[i] = (i < NBLK) ? 0u : 0xFFFFFFFFu;
}

extern "C" void kernel_launch(void* const* d_in, const int* in_sizes, int n_in,
                              void* d_out, int out_size, void* d_ws, size_t ws_size,
                              hipStream_t stream) {
  (void)in_sizes; (void)n_in; (void)out_size; (void)ws_size;
  const float* x      = (const float*)d_in[0];
  const float* W_ih1  = (const float*)d_in[1];
  const float* b_ih1  = (const float*)d_in[2];
  const float* W_hh1  = (const float*)d_in[3];
  const float* b_hh1  = (const float*)d_in[4];
  const float* W_ih2  = (const float*)d_in[5];
  const float* b_ih2  = (const float*)d_in[6];
  const float* W_hh2  = (const float*)d_in[7];
  const float* b_hh2  = (const float*)d_in[8];
  const float* Wg     = (const float*)d_in[9];
  const float* bg     = (const float*)d_in[10];
  const float* Wo1    = (const float*)d_in[11];
  const float* bo1    = (const float*)d_in[12];
  const float* Wo2    = (const float*)d_in[13];
  const float* bo2    = (const float*)d_in[14];

  char* ws = (char*)d_ws;
  size_t off = 0;
  auto alloc = [&](size_t bytes) -> void* {
    void* ptr = ws + off;
    off += (bytes + 255) & ~(size_t)255;
    return ptr;
  };
  short* whh1 = (short*)alloc((size_t)Hh * Hh * 2);
  short* wih2 = (short*)alloc((size_t)Hh * Hh * 2);
  short* whh2 = (short*)alloc((size_t)Hh * Hh * 2);
  short* wg   = (short*)alloc((size_t)Hh * 2 * Hh * 2);
  short* wo1  = (short*)alloc((size_t)Oo * Hh * 2);
  short* wo2  = (short*)alloc((size_t)Oo * Hh * 2);
  short* prex = (short*)alloc((size_t)Bb * Tt * Hh * 2);
  short* h1a  = (short*)alloc((size_t)Bb * Hh * 2);
  short* h1b  = (short*)alloc((size_t)Bb * Hh * 2);
  short* h2bf = (short*)alloc((size_t)Bb * Hh * 2);
  float* h2f  = (float*)alloc((size_t)Bb * Hh * 4);
  float* uf   = (float*)alloc((size_t)Bb * Hh * 4);
  float* ug1f = (float*)alloc((size_t)Bb * Hh * 4);
  float* acc2f= (float*)alloc((size_t)Bb * Hh * 4);
  float* o1f  = (float*)alloc((size_t)Bb * Oo * 4);
  unsigned* flags = (unsigned*)alloc(256 * 4);   // packed: 200 flags in 7 lines

  conv_kernel<<<1024, 256, 0, stream>>>(W_hh1, whh1, Hh * Hh);
  conv_kernel<<<1024, 256, 0, stream>>>(W_ih2, wih2, Hh * Hh);
  conv_kernel<<<1024, 256, 0, stream>>>(W_hh2, whh2, Hh * Hh);
  conv_kernel<<<2048, 256, 0, stream>>>(Wg,    wg,   Hh * 2 * Hh);
  conv_kernel<<<256,  256, 0, stream>>>(Wo1,   wo1,  Oo * Hh);
  conv_kernel<<<256,  256, 0, stream>>>(Wo2,   wo2,  Oo * Hh);
  init_kernel<<<512, 256, 0, stream>>>(h1a, h1b, h2bf, h2f, uf, flags);
  prex_kernel<<<8192, 256, 0, stream>>>(x, W_ih1, b_ih1, b_hh1, prex);

  RP p;
  p.h1a = h1a; p.h1b = h1b; p.h2bf = h2bf;
  p.h2f = h2f; p.uf = uf; p.ug1f = ug1f; p.acc2f = acc2f; p.o1f = o1f;
  p.prex = prex;
  p.whh1 = whh1; p.wih2 = wih2; p.whh2 = whh2;
  p.wg = wg; p.wo1 = wo1; p.wo2 = wo2;
  p.b_ih2 = b_ih2; p.b_hh2 = b_hh2;
  p.bg = bg; p.bo1 = bo1; p.bo2 = bo2;
  p.out = (float*)d_out;
  p.flags = flags;

  rnn_kernel<<<NBLK, 256, 0, stream>>>(p);
}